// Round 7
// baseline (363.090 us; speedup 1.0000x reference)
//
#include <hip/hip_runtime.h>
#include <hip/hip_bf16.h>

#define TOKENS 16384
#define DMODEL 4096
#define NCH 8
#define CH 512
#define BM 64

typedef short s16x8 __attribute__((ext_vector_type(8)));
typedef float f32x4 __attribute__((ext_vector_type(4)));

__device__ __forceinline__ unsigned short f2bf(float f) {
    unsigned u = __float_as_uint(f);
    u += 0x7fffu + ((u >> 16) & 1u);
    return (unsigned short)(u >> 16);
}

// tanh-form GELU via single v_exp: gelu(x) = x - x/(e+1), e = exp(1.5957691*(x+0.044715x^3))
__device__ __forceinline__ float gelu_fast(float x) {
    float u = 1.5957691216057308f * x * (1.0f + 0.044715f * x * x);
    float e = __expf(u);
    return x - x * __builtin_amdgcn_rcpf(e + 1.0f);
}

// ---------------------------------------------------------------------------
// K0: weight prep into MFMA-fragment-packed layout.
// w[n][c][d] fp32 -> P[n][kt][nb][lane][8] bf16; the 16B at (kt,nb,lane=kg*16+l15)
// holds W[kt*32+kg*8+j][nb*16+l15], j=0..7. B-frag loads become 64-lane
// contiguous 1KB reads.
// ---------------------------------------------------------------------------
__global__ __launch_bounds__(256)
void wprep_kernel(const float* __restrict__ w1, const float* __restrict__ w2,
                  unsigned short* __restrict__ p1, unsigned short* __restrict__ p2)
{
    const int lane = threadIdx.x;          // 0..63
    const int sub  = threadIdx.y;          // 0..3
    const int kt   = blockIdx.x;           // 0..15
    const int nb   = blockIdx.y * 4 + sub; // 0..31
    const int which = blockIdx.z >> 3;
    const int n     = blockIdx.z & 7;

    const int kg  = lane >> 4;
    const int l15 = lane & 15;

    const float* src = (which ? w2 : w1) + (size_t)n * CH * CH;
    unsigned short* dst = (which ? p2 : p1) + (size_t)n * CH * CH
                        + ((size_t)(kt * 32 + nb) * 64 + lane) * 8;

    unsigned short v[8];
#pragma unroll
    for (int j = 0; j < 8; ++j)
        v[j] = f2bf(src[(size_t)(kt * 32 + kg * 8 + j) * CH + nb * 16 + l15]);

    uint4 q;
    q.x = (unsigned)v[0] | ((unsigned)v[1] << 16);
    q.y = (unsigned)v[2] | ((unsigned)v[3] << 16);
    q.z = (unsigned)v[4] | ((unsigned)v[5] << 16);
    q.w = (unsigned)v[6] | ((unsigned)v[7] << 16);
    *(uint4*)dst = q;
}

// ---------------------------------------------------------------------------
// One N-half GEMM pass over K=512 (16 kt-steps), acc 4x4 (64 regs).
// FULLY UNROLLED k-loop: A ping-pong prefetched BEFORE mm (targets the other
// buffer), B rotating buffer reloaded AFTER mm (same buffer just consumed —
// reloading before mm was round 6's correctness bug: program order made the
// MFMAs read kt+BDEPTH). All buffer indices are compile-time constants.
// s_setprio(1) around each MFMA cluster (T5).
// ---------------------------------------------------------------------------
template<int BDEPTH>
__device__ __forceinline__ void gemm_half(
    const unsigned short* __restrict__ wp,   // packed panel base (chunk n)
    const unsigned char* lds,
    int nbase,                               // wid*8 + half*4
    int lane, int l15, int kg,
    f32x4 (&acc)[4][4])
{
    s16x8 B[BDEPTH][4], A[2][4];
    auto loadB = [&](int buf, int kt) {
        const unsigned short* p = wp + ((size_t)(kt * 32 + nbase) * 64 + lane) * 8;
#pragma unroll
        for (int ni = 0; ni < 4; ++ni)
            B[buf][ni] = *(const s16x8*)(p + (size_t)ni * 64 * 8);
    };
    auto loadA = [&](int buf, int kt) {
#pragma unroll
        for (int mi = 0; mi < 4; ++mi) {
            int r = mi * 16 + l15;
            int byte = ((r * CH + kt * 32 + kg * 8) * 2) ^ ((r & 7) << 4);
            A[buf][mi] = *(const s16x8*)(lds + byte);
        }
    };

#pragma unroll
    for (int i = 0; i < BDEPTH; ++i) loadB(i, i);
    loadA(0, 0);

#pragma unroll
    for (int k = 0; k < 16; ++k) {
        if (k < 15) loadA((k + 1) & 1, k + 1);   // other buffer: safe pre-mm
        __builtin_amdgcn_s_setprio(1);
#pragma unroll
        for (int ni = 0; ni < 4; ++ni)
#pragma unroll
            for (int mi = 0; mi < 4; ++mi)
                acc[mi][ni] = __builtin_amdgcn_mfma_f32_16x16x32_bf16(
                    A[k & 1][mi], B[k % BDEPTH][ni], acc[mi][ni], 0, 0, 0);
        __builtin_amdgcn_s_setprio(0);
        if (k < 16 - BDEPTH) loadB(k % BDEPTH, k + BDEPTH);  // reload consumed buf AFTER mm
    }
}

// ---------------------------------------------------------------------------
// K1: fused chunk MLP.  grid = (TOKENS/BM, NCH) — tile fastest so co-resident
// blocks share a chunk's weight panel (L2 dedup). block = 256 (4 waves),
// wave owns a 128-wide N slice computed as two 64-wide passes (acc 4x4).
// ---------------------------------------------------------------------------
__global__ __launch_bounds__(256, 2)
void mlp_kernel(const float* __restrict__ x,
                const unsigned short* __restrict__ p1,
                const unsigned short* __restrict__ p2,
                const float* __restrict__ b1,
                const float* __restrict__ b2,
                float* __restrict__ mid)
{
    __shared__ unsigned char lds[BM * CH * 2];   // 64 KB, Xc then H1 (aliased)
    const int tile = blockIdx.x;
    const int n    = blockIdx.y;
    const int tid  = threadIdx.x;
    const int wid  = tid >> 6;
    const int lane = tid & 63;
    const int row0 = tile * BM;

    // ---- stage Xc (fp32 -> bf16, swizzled) ----
    {
        const float* xc = x + (size_t)row0 * DMODEL + n * CH;
#pragma unroll
        for (int it = 0; it < 32; ++it) {
            int f = it * 256 + tid;
            int r = f >> 7;
            int c = (f & 127) << 2;
            const float4 v = *(const float4*)(xc + (size_t)r * DMODEL + c);
            unsigned lo = (unsigned)f2bf(v.x) | ((unsigned)f2bf(v.y) << 16);
            unsigned hi = (unsigned)f2bf(v.z) | ((unsigned)f2bf(v.w) << 16);
            int byte = ((r * CH + c) * 2) ^ ((r & 7) << 4);
            *(uint2*)(lds + byte) = make_uint2(lo, hi);
        }
    }
    __syncthreads();

    const int nwoff = wid * 128;
    const int l15   = lane & 15;
    const int kg    = lane >> 4;

    float b1v[8], b2v[8];   // [half*4 + ni]
#pragma unroll
    for (int h = 0; h < 2; ++h)
#pragma unroll
        for (int ni = 0; ni < 4; ++ni) {
            int col = n * CH + nwoff + h * 64 + ni * 16 + l15;
            b1v[h * 4 + ni] = b1[col];
            b2v[h * 4 + ni] = b2[col];
        }

    const unsigned short* p1n = p1 + (size_t)n * CH * CH;
    const unsigned short* p2n = p2 + (size_t)n * CH * CH;

    f32x4 acc[4][4];
    auto zacc = [&]() {
#pragma unroll
        for (int mi = 0; mi < 4; ++mi)
#pragma unroll
            for (int ni = 0; ni < 4; ++ni)
                acc[mi][ni] = (f32x4){0.f, 0.f, 0.f, 0.f};
    };

    // ================= GEMM1 =================
    zacc();
    gemm_half<3>(p1n, lds, wid * 8 + 0, lane, l15, kg, acc);

    // pass0: bias + GELU -> packed bf16 register stash (32 u32)
    unsigned g0[4][4][2];
#pragma unroll
    for (int mi = 0; mi < 4; ++mi)
#pragma unroll
        for (int ni = 0; ni < 4; ++ni)
#pragma unroll
            for (int j = 0; j < 2; ++j) {
                float v0 = gelu_fast(acc[mi][ni][2 * j]     + b1v[ni]);
                float v1 = gelu_fast(acc[mi][ni][2 * j + 1] + b1v[ni]);
                g0[mi][ni][j] = (unsigned)f2bf(v0) | ((unsigned)f2bf(v1) << 16);
            }

    zacc();
    gemm_half<2>(p1n, lds, wid * 8 + 4, lane, l15, kg, acc);

    __syncthreads();   // all waves done reading Xc

    // write H1 (bf16, swizzled) — pass0 from stash, pass1 from acc
#pragma unroll
    for (int mi = 0; mi < 4; ++mi)
#pragma unroll
        for (int ni = 0; ni < 4; ++ni)
#pragma unroll
            for (int j = 0; j < 2; ++j) {
                int col  = nwoff + ni * 16 + l15;
                int row  = mi * 16 + kg * 4 + 2 * j;
                int byte0 = ((row * CH + col) * 2) ^ ((row & 7) << 4);
                *(unsigned short*)(lds + byte0) = (unsigned short)(g0[mi][ni][j] & 0xffff);
                int row1 = row + 1;
                int byte1 = ((row1 * CH + col) * 2) ^ ((row1 & 7) << 4);
                *(unsigned short*)(lds + byte1) = (unsigned short)(g0[mi][ni][j] >> 16);
            }
#pragma unroll
    for (int mi = 0; mi < 4; ++mi)
#pragma unroll
        for (int ni = 0; ni < 4; ++ni)
#pragma unroll
            for (int r = 0; r < 4; ++r) {
                float v = gelu_fast(acc[mi][ni][r] + b1v[4 + ni]);
                int col  = nwoff + 64 + ni * 16 + l15;
                int row  = mi * 16 + kg * 4 + r;
                int byte = ((row * CH + col) * 2) ^ ((row & 7) << 4);
                *(unsigned short*)(lds + byte) = f2bf(v);
            }
    __syncthreads();

    // ================= GEMM2 =================
    const float* xr = x   + (size_t)row0 * DMODEL + n * CH;
    float*       mr = mid + (size_t)row0 * DMODEL + n * CH;

#pragma unroll
    for (int h = 0; h < 2; ++h) {
        zacc();
        if (h == 0) gemm_half<3>(p2n, lds, wid * 8 + 0, lane, l15, kg, acc);
        else        gemm_half<3>(p2n, lds, wid * 8 + 4, lane, l15, kg, acc);
#pragma unroll
        for (int mi = 0; mi < 4; ++mi)
#pragma unroll
            for (int ni = 0; ni < 4; ++ni)
#pragma unroll
                for (int r = 0; r < 4; ++r) {
                    int row = mi * 16 + kg * 4 + r;
                    int col = nwoff + h * 64 + ni * 16 + l15;
                    float v = acc[mi][ni][r] + b2v[h * 4 + ni] + xr[(size_t)row * DMODEL + col];
                    mr[(size_t)row * DMODEL + col] = v;
                }
    }
}

// ---------------------------------------------------------------------------
// K2: in-place LayerNorm over rows of `out`.
// ---------------------------------------------------------------------------
__global__ __launch_bounds__(256)
void ln_kernel(float* __restrict__ out,
               const float* __restrict__ g,
               const float* __restrict__ bt)
{
    __shared__ float red[8];
    const int row = blockIdx.x;
    const int tid = threadIdx.x;
    float* p = out + (size_t)row * DMODEL;

    float4 v[4];
    float s = 0.f, ss = 0.f;
#pragma unroll
    for (int i = 0; i < 4; ++i) {
        v[i] = *(const float4*)(p + (i * 256 + tid) * 4);
        s  += v[i].x + v[i].y + v[i].z + v[i].w;
        ss += v[i].x * v[i].x + v[i].y * v[i].y + v[i].z * v[i].z + v[i].w * v[i].w;
    }
#pragma unroll
    for (int o = 32; o > 0; o >>= 1) {
        s  += __shfl_xor(s, o, 64);
        ss += __shfl_xor(ss, o, 64);
    }
    const int wid = tid >> 6, lane = tid & 63;
    if (lane == 0) { red[wid] = s; red[4 + wid] = ss; }
    __syncthreads();
    s  = red[0] + red[1] + red[2] + red[3];
    ss = red[4] + red[5] + red[6] + red[7];
    const float mu   = s * (1.f / DMODEL);
    const float var  = ss * (1.f / DMODEL) - mu * mu;
    const float rstd = rsqrtf(var + 1e-5f);

#pragma unroll
    for (int i = 0; i < 4; ++i) {
        int c = (i * 256 + tid) * 4;
        float4 gv = *(const float4*)(g + c);
        float4 bv = *(const float4*)(bt + c);
        float4 o;
        o.x = (v[i].x - mu) * rstd * gv.x + bv.x;
        o.y = (v[i].y - mu) * rstd * gv.y + bv.y;
        o.z = (v[i].z - mu) * rstd * gv.z + bv.z;
        o.w = (v[i].w - mu) * rstd * gv.w + bv.w;
        *(float4*)(p + c) = o;
    }
}

// ---------------------------------------------------------------------------
extern "C" void kernel_launch(void* const* d_in, const int* in_sizes, int n_in,
                              void* d_out, int out_size, void* d_ws, size_t ws_size,
                              hipStream_t stream)
{
    const float* x    = (const float*)d_in[0];
    const float* w1   = (const float*)d_in[1];
    const float* b1   = (const float*)d_in[2];
    const float* w2   = (const float*)d_in[3];
    const float* b2   = (const float*)d_in[4];
    const float* ln_g = (const float*)d_in[5];
    const float* ln_b = (const float*)d_in[6];
    float* out = (float*)d_out;

    unsigned short* p1 = (unsigned short*)d_ws;           // 4 MiB packed W1
    unsigned short* p2 = p1 + (size_t)NCH * CH * CH;      // 4 MiB packed W2

    wprep_kernel<<<dim3(16, 8, 16), dim3(64, 4), 0, stream>>>(w1, w2, p1, p2);
    mlp_kernel<<<dim3(TOKENS / BM, NCH), dim3(256), 0, stream>>>(x, p1, p2, b1, b2, out);
    ln_kernel<<<dim3(TOKENS), dim3(256), 0, stream>>>(out, ln_g, ln_b);
}